// Round 5
// baseline (151.313 us; speedup 1.0000x reference)
//
#include <hip/hip_runtime.h>
#include <math.h>

typedef _Float16 half8 __attribute__((ext_vector_type(8)));
typedef float floatx4 __attribute__((ext_vector_type(4)));

union U16 { uint4 u; half8 h; };

// ---------------------------------------------------------------------------
// prep: 101 blocks x 512 threads.
//  [0,32):   R granules: d0=8*bid, K=1024 split in halves, LDS reduce,
//            R2Pk[bid*256+h] = f16 granule {R[d0..d0+8][h]} (d=255 -> 0)
//  [32,96):  a rows r0=8*(bid-32) (f32, +Whb) and bvPk f16 granule
//  [96,100): WmT2 f16 granule pack (kb*256+h = Wm[kb*8..+8][h])
//  [100]:    WoPk granules + zero-pad R2Pk granules 32..40
// ---------------------------------------------------------------------------
__global__ __launch_bounds__(512) void k_prep(
    const float* __restrict__ hs, const float* __restrict__ Wh,
    const float* __restrict__ Whb, const float* __restrict__ Wo,
    float* __restrict__ a, uint4* __restrict__ WmT2, uint4* __restrict__ bvPk,
    uint4* __restrict__ R2Pk, uint4* __restrict__ WoPk)
{
  __shared__ __align__(16) char pool[40960];
  int bid = blockIdx.x, tid = threadIdx.x;

  if (bid < 32) {                        // ---- R granules ----
    float (*tbl)[8] = (float(*)[8])pool;            // [1024 k][8 d] = 32 KB
    float* part = (float*)(pool + 32768);           // [8 d][256 h] = 8 KB
    int d0 = bid * 8;
    for (int idx = tid; idx < 8192; idx += 512) {
      int k = idx >> 3, dl = idx & 7;
      float e = (float)(k & ~1) * (1.0f / 1024.f);
      float div = powf(10000.f, e);
      float ang = (float)(d0 + dl) / div;
      tbl[k][dl] = (k & 1) ? cosf(ang) : sinf(ang);
    }
    __syncthreads();
    int h = tid & 255, s = tid >> 8;
    float acc[8] = {0, 0, 0, 0, 0, 0, 0, 0};
    for (int kk = 0; kk < 512; ++kk) {
      int k = s * 512 + kk;
      float wv = Wh[k * 256 + h];
      float tr[8];
      *(float4*)&tr[0] = *(const float4*)&tbl[k][0];
      *(float4*)&tr[4] = *(const float4*)&tbl[k][4];
#pragma unroll
      for (int dl = 0; dl < 8; ++dl) acc[dl] = fmaf(tr[dl], wv, acc[dl]);
    }
    if (s) {
#pragma unroll
      for (int dl = 0; dl < 8; ++dl) part[dl * 256 + h] = acc[dl];
    }
    __syncthreads();
    if (!s) {
      U16 v;
#pragma unroll
      for (int dl = 0; dl < 8; ++dl) {
        float sum = acc[dl] + part[dl * 256 + h];
        v.h[dl] = (d0 + dl < 255) ? (_Float16)sum : (_Float16)0.f;
      }
      R2Pk[bid * 256 + h] = v.u;
    }

  } else if (bid < 96) {                 // ---- a (f32) / bv (f16 granules) ----
    float (*xs)[8] = (float(*)[8])pool;             // [256 k][8 r] = 8 KB
    float* pa = (float*)(pool + 8192);              // 8 KB
    float* pb = (float*)(pool + 16384);             // 8 KB
    int r0 = (bid - 32) * 8;
    for (int idx = tid; idx < 2048; idx += 512) {
      int k = idx & 255, r = idx >> 8;
      xs[k][r] = hs[(r0 + r) * 256 + k];
    }
    __syncthreads();
    int h = tid & 255, s = tid >> 8;
    float aa[8] = {0, 0, 0, 0, 0, 0, 0, 0}, bb[8] = {0, 0, 0, 0, 0, 0, 0, 0};
    for (int kk = 0; kk < 128; ++kk) {
      int k = s * 128 + kk;
      float we = Wh[k * 256 + h];
      float wsv = Wh[(256 + k) * 256 + h];
      float wd = Wh[(512 + k) * 256 + h];
      float wA = we + wd, wB = wsv - wd;
      float xr[8];
      *(float4*)&xr[0] = *(const float4*)&xs[k][0];
      *(float4*)&xr[4] = *(const float4*)&xs[k][4];
#pragma unroll
      for (int r = 0; r < 8; ++r) {
        aa[r] = fmaf(xr[r], wA, aa[r]);
        bb[r] = fmaf(xr[r], wB, bb[r]);
      }
    }
    if (s) {
#pragma unroll
      for (int r = 0; r < 8; ++r) { pa[r * 256 + h] = aa[r]; pb[r * 256 + h] = bb[r]; }
    }
    __syncthreads();
    if (!s) {
      float bias = Whb[h];
      U16 v;
#pragma unroll
      for (int r = 0; r < 8; ++r) {
        a[(r0 + r) * 256 + h] = aa[r] + pa[r * 256 + h] + bias;
        v.h[r] = (_Float16)(bb[r] + pb[r * 256 + h]);
      }
      bvPk[(r0 >> 3) * 256 + h] = v.u;
    }

  } else if (bid < 100) {                // ---- WmT2 pack ----
    _Float16 (*T)[256] = (_Float16(*)[256])pool;    // [64 k][256 h] = 32 KB
    int q = bid - 96;
    for (int idx = tid; idx < 16384; idx += 512) {
      int k = idx >> 8, h = idx & 255;
      T[k][h] = (_Float16)Wh[(768 + q * 64 + k) * 256 + h];
    }
    __syncthreads();
    for (int gi = tid; gi < 2048; gi += 512) {
      int kbl = gi >> 8, h = gi & 255;
      U16 v;
#pragma unroll
      for (int e = 0; e < 8; ++e) v.h[e] = T[kbl * 8 + e][h];
      WmT2[(q * 8 + kbl) * 256 + h] = v.u;
    }

  } else {                               // ---- WoPk + R2Pk zero-pad ----
    {
      int kb = tid >> 4, c = tid & 15;   // tid in [0,512) exactly covers it
      U16 v;
#pragma unroll
      for (int e = 0; e < 8; ++e)
        v.h[e] = (c < 5) ? (_Float16)Wo[(kb * 8 + e) * 5 + c] : (_Float16)0.f;
      WoPk[tid] = v.u;
    }
    uint4 z = {0, 0, 0, 0};
    for (int idx = tid; idx < 2048; idx += 512) R2Pk[8192 + idx] = z;
  }
}

// ---------------------------------------------------------------------------
// main: 2048 blocks = (b, i-pair, j-tile 32); 4 waves split h' (64 each).
// K-extended GEMM, K=352: cols [0,256)=Wm (A = x_i.x_j), [256,288)=bv one-hot,
// [288,352)=R one-hot over granule-aligned 64-row d-window. B-granules stream
// from L2 (WmT2/bvPk/R2Pk). acc init = a_i (incl bias) broadcast only.
// Epilogue: tanh -> f16 P (64 rows) in As -> all 4 waves 16-row Wo GEMM.
// ---------------------------------------------------------------------------
__global__ __launch_bounds__(256, 3) void k_main(
    const float* __restrict__ hs, const int* __restrict__ mask,
    const float* __restrict__ a, const uint4* __restrict__ WmT2,
    const uint4* __restrict__ bvPk, const uint4* __restrict__ R2Pk,
    const uint4* __restrict__ WoPk, const float* __restrict__ Wob,
    float* __restrict__ out)
{
  __shared__ __align__(16) _Float16 As[2][32][360];  // 45 KB (352 + 8 pad)

  int bid = blockIdx.x, tid = threadIdx.x;
  int jt = bid & 7, ig = (bid >> 3) & 127, b = bid >> 10;
  int i0 = ig * 2, j0 = jt * 32;
  int lane = tid & 63, w = tid >> 6;
  int c16 = lane & 15, quad = lane >> 4;
  const float* hsb = hs + (size_t)b * 65536;

  // d-window: granule-aligned start, span <= 41 < 64
  int ddmin = j0 - i0 - 1 + 127;
  ddmin = ddmin < 0 ? 0 : (ddmin > 254 ? 254 : ddmin);
  int g0 = ddmin & ~7;

  // ---- acc init: a_i (incl Whb) broadcast ----
  float av[2][4];
#pragma unroll
  for (int i2 = 0; i2 < 2; ++i2)
#pragma unroll
    for (int ht2 = 0; ht2 < 4; ++ht2)
      av[i2][ht2] = a[((size_t)(b * 256 + i0 + i2)) * 256 + 64 * w + 16 * ht2 + c16];
  floatx4 acc[2][2][4];
#pragma unroll
  for (int i2 = 0; i2 < 2; ++i2)
#pragma unroll
    for (int jt2 = 0; jt2 < 2; ++jt2)
#pragma unroll
      for (int ht2 = 0; ht2 < 4; ++ht2)
        acc[i2][jt2][ht2] = (floatx4){av[i2][ht2], av[i2][ht2], av[i2][ht2], av[i2][ht2]};

  // ---- zero ext region (cols 256..352), 12 b128 per row x 64 rows ----
  {
    uint4 z = {0, 0, 0, 0};
    for (int e = tid; e < 768; e += 256) {
      int row = e / 12, q = e - row * 12;
      *(uint4*)(&As[row >> 5][row & 31][256 + q * 8]) = z;
    }
  }

  // ---- A tile (Wm cols): As[i2][j][k] = f16(x_{i0+i2}[k] * x_{j0+j}[k]) ----
  {
    int k8 = (tid & 31) * 8, jb = tid >> 5;
#pragma unroll
    for (int i2 = 0; i2 < 2; ++i2) {
      float4 xi0 = *(const float4*)(hsb + (i0 + i2) * 256 + k8);
      float4 xi1 = *(const float4*)(hsb + (i0 + i2) * 256 + k8 + 4);
#pragma unroll
      for (int m = 0; m < 4; ++m) {
        int j = jb + 8 * m;
        float4 xj0 = *(const float4*)(hsb + (j0 + j) * 256 + k8);
        float4 xj1 = *(const float4*)(hsb + (j0 + j) * 256 + k8 + 4);
        half8 p = {(_Float16)(xi0.x * xj0.x), (_Float16)(xi0.y * xj0.y),
                   (_Float16)(xi0.z * xj0.z), (_Float16)(xi0.w * xj0.w),
                   (_Float16)(xi1.x * xj1.x), (_Float16)(xi1.y * xj1.y),
                   (_Float16)(xi1.z * xj1.z), (_Float16)(xi1.w * xj1.w)};
        *(half8*)(&As[i2][j][k8]) = p;
      }
    }
  }
  __syncthreads();  // zeros visible before one-hot writes

  // ---- one-hot writes: row (i2,jl): col 256+jl = 1; col 288+(dd-g0) = 1 ----
  if (tid < 64) {
    int i2 = tid >> 5, jl = tid & 31;
    int dd = j0 + jl - i0 - i2;
    dd = dd < -127 ? -127 : (dd > 127 ? 127 : dd);
    dd += 127;
    As[i2][jl][256 + jl] = (_Float16)1.f;
    As[i2][jl][288 + (dd - g0)] = (_Float16)1.f;
  }
  __syncthreads();

  // ---- K loop: 11 ksteps of 32; B-granules from L2, prefetch 1 ahead ----
  const int hbase = 64 * w + c16;
  const uint4* bvBase = bvPk + (((b * 256 + j0) >> 3) + quad) * 256;
  const uint4* rBase = R2Pk + ((g0 >> 3) + quad) * 256;
  U16 bg[4], bgn[4];
#pragma unroll
  for (int ht2 = 0; ht2 < 4; ++ht2)
    bg[ht2].u = WmT2[quad * 256 + hbase + 16 * ht2];
#pragma unroll 1
  for (int kb32 = 0; kb32 < 11; ++kb32) {
    if (kb32 < 10) {
      const uint4* bp;
      int nk = kb32 + 1;
      if (nk < 8)       bp = WmT2 + (nk * 4 + quad) * 256;
      else if (nk == 8) bp = bvBase;
      else              bp = rBase + (nk - 9) * 1024;
#pragma unroll
      for (int ht2 = 0; ht2 < 4; ++ht2) bgn[ht2].u = bp[hbase + 16 * ht2];
    }
    half8 af[2][2];
#pragma unroll
    for (int i2 = 0; i2 < 2; ++i2)
#pragma unroll
      for (int jt2 = 0; jt2 < 2; ++jt2)
        af[i2][jt2] =
            *(const half8*)(&As[i2][jt2 * 16 + c16][kb32 * 32 + quad * 8]);
#pragma unroll
    for (int i2 = 0; i2 < 2; ++i2)
#pragma unroll
      for (int jt2 = 0; jt2 < 2; ++jt2)
#pragma unroll
        for (int ht2 = 0; ht2 < 4; ++ht2)
          acc[i2][jt2][ht2] = __builtin_amdgcn_mfma_f32_16x16x32_f16(
              af[i2][jt2], bg[ht2].h, acc[i2][jt2][ht2], 0, 0, 0);
#pragma unroll
    for (int t = 0; t < 4; ++t) bg[t] = bgn[t];
  }

  __syncthreads();  // all A-frag reads complete before P overwrites As

  // ---- P = tanh(acc) -> f16 into As cols [0,256) ----
#pragma unroll
  for (int i2 = 0; i2 < 2; ++i2)
#pragma unroll
    for (int jt2 = 0; jt2 < 2; ++jt2)
#pragma unroll
      for (int ht2 = 0; ht2 < 4; ++ht2) {
        int hp = 64 * w + 16 * ht2 + c16;
#pragma unroll
        for (int r = 0; r < 4; ++r) {
          int jl = jt2 * 16 + quad * 4 + r;
          float x = acc[i2][jt2][ht2][r];
          float t = 1.f - 2.f / (__expf(2.f * x) + 1.f);  // tanh, inf-safe
          As[i2][jl][hp] = (_Float16)t;
        }
      }
  __syncthreads();

  // ---- epilogue GEMM: wave w -> P rows [16w,16w+16) x 16c, K=256 ----
  U16 wog[8];
#pragma unroll
  for (int s = 0; s < 8; ++s) wog[s].u = WoPk[(s * 4 + quad) * 16 + c16];
  floatx4 accE = {0.f, 0.f, 0.f, 0.f};
  int arow = 16 * w + c16;
  int i2a = arow >> 5, jla = arow & 31;
#pragma unroll
  for (int s = 0; s < 8; ++s) {
    half8 ae = *(const half8*)(&As[i2a][jla][s * 32 + quad * 8]);
    accE = __builtin_amdgcn_mfma_f32_16x16x32_f16(ae, wog[s].h, accE, 0, 0, 0);
  }

  const int* mb = mask + b * 256;
  float wob = (c16 < 5) ? Wob[c16] : 0.f;
#pragma unroll
  for (int r = 0; r < 4; ++r) {
    int grow = 16 * w + quad * 4 + r;
    int ii = i0 + (grow >> 5), jg = j0 + (grow & 31);
    float v = accE[r] + wob;
    if (!(mb[ii] && mb[jg])) v = -INFINITY;
    if (jg < ii) v -= 1e12f;
    if (c16 < 5) out[(((size_t)b * 5 + c16) * 256 + ii) * 256 + jg] = v;
  }
}

extern "C" void kernel_launch(void* const* d_in, const int* in_sizes, int n_in,
                              void* d_out, int out_size, void* d_ws, size_t ws_size,
                              hipStream_t stream) {
  const float* hs   = (const float*)d_in[0];
  const int*   mask = (const int*)d_in[1];
  const float* Wh_w = (const float*)d_in[2];
  const float* Wh_b = (const float*)d_in[3];
  const float* Wo_w = (const float*)d_in[4];
  const float* Wo_b = (const float*)d_in[5];

  char* ws = (char*)d_ws;
  float* a    = (float*)(ws + 0);        // 512*256*4  = 524288
  uint4* WmT2 = (uint4*)(ws + 524288);   // 32*256*16  = 131072
  uint4* bvPk = (uint4*)(ws + 655360);   // 64*256*16  = 262144
  uint4* R2Pk = (uint4*)(ws + 917504);   // 40*256*16  = 163840
  uint4* WoPk = (uint4*)(ws + 1081344);  // 512*16     =   8192

  k_prep<<<101, 512, 0, stream>>>(hs, Wh_w, Wh_b, Wo_w, a, WmT2, bvPk, R2Pk, WoPk);
  k_main<<<2048, 256, 0, stream>>>(hs, mask, a, WmT2, bvPk, R2Pk, WoPk, Wo_b,
                                   (float*)d_out);
}

// Round 7
// 132.219 us; speedup vs baseline: 1.1444x; 1.1444x over previous
//
#include <hip/hip_runtime.h>
#include <math.h>

typedef _Float16 half8 __attribute__((ext_vector_type(8)));
typedef __fp16 fp16x2 __attribute__((ext_vector_type(2)));
typedef float floatx4 __attribute__((ext_vector_type(4)));

union U16 { uint4 u; half8 h; fp16x2 p[4]; };

// ---------------------------------------------------------------------------
// prep (R4's proven version): 133 blocks x 512 threads.
//  [0,64):    R rows d0=4*bid..+4, K=1024 split across halves, LDS reduce
//  [64,128):  a/bv rows r0=8*(bid-64); a += Whb
//  [128,132): WmT2 f16 granule pack: WmT2[kb*256+h] = Wm[kb*8..+8][h]
//  [132]:     WoPk f16 granule pack (c<5 real, else 0)
// ---------------------------------------------------------------------------
__global__ __launch_bounds__(512) void k_prep(
    const float* __restrict__ hs, const float* __restrict__ Wh,
    const float* __restrict__ Whb, const float* __restrict__ Wo,
    float* __restrict__ R, float* __restrict__ a, float* __restrict__ bv,
    uint4* __restrict__ WmT2, uint4* __restrict__ WoPk)
{
  __shared__ __align__(16) char pool[32768];
  int bid = blockIdx.x, tid = threadIdx.x;

  if (bid < 64) {                        // ---- R ----
    float (*tbl)[4] = (float(*)[4])pool;            // [1024 k][4 d] = 16 KB
    float* part = (float*)(pool + 16384);           // [4 d][256 h] = 4 KB
    int d0 = bid * 4;
    for (int idx = tid; idx < 4096; idx += 512) {
      int k = idx >> 2, dl = idx & 3;
      float e = (float)(k & ~1) * (1.0f / 1024.f);
      float div = powf(10000.f, e);
      float ang = (float)(d0 + dl) / div;
      tbl[k][dl] = (k & 1) ? cosf(ang) : sinf(ang);
    }
    __syncthreads();
    int h = tid & 255, s = tid >> 8;
    float acc[4] = {0.f, 0.f, 0.f, 0.f};
    for (int kk = 0; kk < 512; ++kk) {
      int k = s * 512 + kk;
      float wv = Wh[k * 256 + h];
      float4 tr = *(const float4*)&tbl[k][0];
      acc[0] = fmaf(tr.x, wv, acc[0]);
      acc[1] = fmaf(tr.y, wv, acc[1]);
      acc[2] = fmaf(tr.z, wv, acc[2]);
      acc[3] = fmaf(tr.w, wv, acc[3]);
    }
    if (s) {
#pragma unroll
      for (int dl = 0; dl < 4; ++dl) part[dl * 256 + h] = acc[dl];
    }
    __syncthreads();
    if (!s) {
#pragma unroll
      for (int dl = 0; dl < 4; ++dl)
        if (d0 + dl < 255)
          R[(d0 + dl) * 256 + h] = acc[dl] + part[dl * 256 + h];
    }

  } else if (bid < 128) {                // ---- a / bv (a includes Whb) ----
    float (*xs)[8] = (float(*)[8])pool;             // [256 k][8 r] = 8 KB
    float* pa = (float*)(pool + 8192);              // 8 KB
    float* pb = (float*)(pool + 16384);             // 8 KB
    int r0 = (bid - 64) * 8;
    for (int idx = tid; idx < 2048; idx += 512) {
      int k = idx & 255, r = idx >> 8;
      xs[k][r] = hs[(r0 + r) * 256 + k];
    }
    __syncthreads();
    int h = tid & 255, s = tid >> 8;
    float aa[8] = {0, 0, 0, 0, 0, 0, 0, 0}, bb[8] = {0, 0, 0, 0, 0, 0, 0, 0};
    for (int kk = 0; kk < 128; ++kk) {
      int k = s * 128 + kk;
      float we = Wh[k * 256 + h];
      float wsv = Wh[(256 + k) * 256 + h];
      float wd = Wh[(512 + k) * 256 + h];
      float wA = we + wd, wB = wsv - wd;
      float xr[8];
      *(float4*)&xr[0] = *(const float4*)&xs[k][0];
      *(float4*)&xr[4] = *(const float4*)&xs[k][4];
#pragma unroll
      for (int r = 0; r < 8; ++r) {
        aa[r] = fmaf(xr[r], wA, aa[r]);
        bb[r] = fmaf(xr[r], wB, bb[r]);
      }
    }
    if (s) {
#pragma unroll
      for (int r = 0; r < 8; ++r) { pa[r * 256 + h] = aa[r]; pb[r * 256 + h] = bb[r]; }
    }
    __syncthreads();
    if (!s) {
      float bias = Whb[h];
#pragma unroll
      for (int r = 0; r < 8; ++r) {
        a[(r0 + r) * 256 + h] = aa[r] + pa[r * 256 + h] + bias;
        bv[(r0 + r) * 256 + h] = bb[r] + pb[r * 256 + h];
      }
    }

  } else if (bid < 132) {                // ---- WmT2 pack ----
    _Float16 (*T)[256] = (_Float16(*)[256])pool;    // [64 k][256 h] = 32 KB
    int q = bid - 128;
    for (int idx = tid; idx < 16384; idx += 512) {
      int k = idx >> 8, h = idx & 255;
      T[k][h] = (_Float16)Wh[(768 + q * 64 + k) * 256 + h];
    }
    __syncthreads();
    for (int gi = tid; gi < 2048; gi += 512) {
      int kbl = gi >> 8, h = gi & 255;
      U16 v;
#pragma unroll
      for (int e = 0; e < 8; ++e) v.h[e] = T[kbl * 8 + e][h];
      WmT2[(q * 8 + kbl) * 256 + h] = v.u;
    }

  } else {                               // ---- WoPk pack ----
    int kb = tid >> 4, c = tid & 15;     // tid in [0,512) covers 32x16
    U16 v;
#pragma unroll
    for (int e = 0; e < 8; ++e)
      v.h[e] = (c < 5) ? (_Float16)Wo[(kb * 8 + e) * 5 + c] : (_Float16)0.f;
    WoPk[tid] = v.u;
  }
}

// ---------------------------------------------------------------------------
// main: 2048 blocks x 512 thr = (b, i-pair, j-tile 32); 8 waves, wave w owns
// h' cols [32w, 32w+32). acc = 32 f32/lane -> launch_bounds(512,6): target
// 6 waves/SIMD = 3 blocks/CU (75% occ). K-loop barrier-free, B from L2 with
// prefetch-1. Epilogue: tanh -> f16 P in As -> waves 0..3 do Wo GEMM.
// ---------------------------------------------------------------------------
__global__ __launch_bounds__(512, 6) void k_main(
    const float* __restrict__ hs, const int* __restrict__ mask,
    const float* __restrict__ R, const float* __restrict__ a,
    const float* __restrict__ bvec, const uint4* __restrict__ WmT2,
    const uint4* __restrict__ WoPk, const float* __restrict__ Wob,
    float* __restrict__ out)
{
  __shared__ __align__(16) _Float16 As[2][32][264];  // 33.8 KB

  int bid = blockIdx.x, tid = threadIdx.x;
  int jt = bid & 7, ig = (bid >> 3) & 127, b = bid >> 10;
  int i0 = ig * 2, j0 = jt * 32;
  int lane = tid & 63, w = tid >> 6;   // w in [0,8)
  int c16 = lane & 15, quad = lane >> 4;
  const float* hsb = hs + (size_t)b * 65536;

  // ---- A tile build: As[i2][j][k] = f16(x_{i0+i2}[k]*x_{j0+j}[k]) ----
  {
    int k8 = (tid & 31) * 8, rb = tid >> 5;  // rb in [0,16)
    float4 xi00 = *(const float4*)(hsb + i0 * 256 + k8);
    float4 xi01 = *(const float4*)(hsb + i0 * 256 + k8 + 4);
    float4 xi10 = *(const float4*)(hsb + (i0 + 1) * 256 + k8);
    float4 xi11 = *(const float4*)(hsb + (i0 + 1) * 256 + k8 + 4);
#pragma unroll
    for (int m = 0; m < 4; ++m) {
      int row = rb + 16 * m;             // [0,64)
      int i2 = row >> 5, j = row & 31;
      float4 xj0 = *(const float4*)(hsb + (j0 + j) * 256 + k8);
      float4 xj1 = *(const float4*)(hsb + (j0 + j) * 256 + k8 + 4);
      float4 y0 = i2 ? xi10 : xi00;
      float4 y1 = i2 ? xi11 : xi01;
      U16 v;
      v.p[0] = __builtin_amdgcn_cvt_pkrtz(y0.x * xj0.x, y0.y * xj0.y);
      v.p[1] = __builtin_amdgcn_cvt_pkrtz(y0.z * xj0.z, y0.w * xj0.w);
      v.p[2] = __builtin_amdgcn_cvt_pkrtz(y1.x * xj1.x, y1.y * xj1.y);
      v.p[3] = __builtin_amdgcn_cvt_pkrtz(y1.z * xj1.z, y1.w * xj1.w);
      *(uint4*)(&As[i2][j][k8]) = v.u;
    }
  }

  // ---- acc init: a_i(+bias) + bv_j + R_{j-i} (latency hidden by TLP) ----
  int hb = 32 * w + c16;
  float av0[2], av1[2];
#pragma unroll
  for (int i2 = 0; i2 < 2; ++i2) {
    const float* ap = a + ((size_t)(b * 256 + i0 + i2)) * 256 + hb;
    av0[i2] = ap[0];
    av1[i2] = ap[16];
  }
  floatx4 acc[2][2][2];  // [i2][jt2][ct2]
#pragma unroll
  for (int jt2 = 0; jt2 < 2; ++jt2) {
#pragma unroll
    for (int r = 0; r < 4; ++r) {
      int jg = j0 + jt2 * 16 + quad * 4 + r;
      const float* bp = bvec + ((size_t)(b * 256 + jg)) * 256 + hb;
      float b0 = bp[0], b1 = bp[16];
#pragma unroll
      for (int i2 = 0; i2 < 2; ++i2) {
        int dd = jg - i0 - i2;
        dd = dd < -127 ? -127 : (dd > 127 ? 127 : dd);
        dd += 127;
        const float* rp = R + (size_t)dd * 256 + hb;
        acc[i2][jt2][0][r] = av0[i2] + b0 + rp[0];
        acc[i2][jt2][1][r] = av1[i2] + b1 + rp[16];
      }
    }
  }
  __syncthreads();

  // ---- K loop: 8 ksteps of 32; B-granules from L2 with prefetch-1 ----
  U16 bg0, bg1, bn0, bn1;
  {
    const uint4* wp = WmT2 + quad * 256 + hb;
    bg0.u = wp[0];
    bg1.u = wp[16];
  }
#pragma unroll 1
  for (int ks = 0; ks < 8; ++ks) {
    if (ks < 7) {
      const uint4* wp = WmT2 + ((ks + 1) * 4 + quad) * 256 + hb;
      bn0.u = wp[0];
      bn1.u = wp[16];
    }
    half8 af[2][2];
#pragma unroll
    for (int i2 = 0; i2 < 2; ++i2)
#pragma unroll
      for (int jt2 = 0; jt2 < 2; ++jt2)
        af[i2][jt2] =
            *(const half8*)(&As[i2][jt2 * 16 + c16][ks * 32 + quad * 8]);
#pragma unroll
    for (int i2 = 0; i2 < 2; ++i2)
#pragma unroll
      for (int jt2 = 0; jt2 < 2; ++jt2) {
        acc[i2][jt2][0] = __builtin_amdgcn_mfma_f32_16x16x32_f16(
            af[i2][jt2], bg0.h, acc[i2][jt2][0], 0, 0, 0);
        acc[i2][jt2][1] = __builtin_amdgcn_mfma_f32_16x16x32_f16(
            af[i2][jt2], bg1.h, acc[i2][jt2][1], 0, 0, 0);
      }
    bg0 = bn0;
    bg1 = bn1;
  }
  __syncthreads();  // all A-frag reads done before P overwrites As

  // ---- P = tanh(acc) -> f16 into As ----
#pragma unroll
  for (int i2 = 0; i2 < 2; ++i2)
#pragma unroll
    for (int jt2 = 0; jt2 < 2; ++jt2)
#pragma unroll
      for (int ct2 = 0; ct2 < 2; ++ct2) {
        int hp = hb + 16 * ct2;
#pragma unroll
        for (int r = 0; r < 4; ++r) {
          int jl = jt2 * 16 + quad * 4 + r;
          float x = acc[i2][jt2][ct2][r];
          float t = 1.f - 2.f / (__expf(2.f * x) + 1.f);  // tanh, inf-safe
          As[i2][jl][hp] = (_Float16)t;
        }
      }
  __syncthreads();

  // ---- epilogue (waves 0..3): P rows [16w,16w+16) x 16c, K=256 ----
  if (w < 4) {
    U16 wog[8];
#pragma unroll
    for (int s = 0; s < 8; ++s) wog[s].u = WoPk[(s * 4 + quad) * 16 + c16];
    floatx4 accE = {0.f, 0.f, 0.f, 0.f};
    int arow = 16 * w + c16;
    int i2a = arow >> 5, jla = arow & 31;
#pragma unroll
    for (int s = 0; s < 8; ++s) {
      half8 ae = *(const half8*)(&As[i2a][jla][s * 32 + quad * 8]);
      accE = __builtin_amdgcn_mfma_f32_16x16x32_f16(ae, wog[s].h, accE, 0, 0, 0);
    }
    const int* mb = mask + b * 256;
    float wob = (c16 < 5) ? Wob[c16] : 0.f;
#pragma unroll
    for (int r = 0; r < 4; ++r) {
      int grow = 16 * w + quad * 4 + r;
      int ii = i0 + (grow >> 5), jg = j0 + (grow & 31);
      float v = accE[r] + wob;
      if (!(mb[ii] && mb[jg])) v = -INFINITY;
      if (jg < ii) v -= 1e12f;
      if (c16 < 5) out[(((size_t)b * 5 + c16) * 256 + ii) * 256 + jg] = v;
    }
  }
}

extern "C" void kernel_launch(void* const* d_in, const int* in_sizes, int n_in,
                              void* d_out, int out_size, void* d_ws, size_t ws_size,
                              hipStream_t stream) {
  const float* hs   = (const float*)d_in[0];
  const int*   mask = (const int*)d_in[1];
  const float* Wh_w = (const float*)d_in[2];
  const float* Wh_b = (const float*)d_in[3];
  const float* Wo_w = (const float*)d_in[4];
  const float* Wo_b = (const float*)d_in[5];

  char* ws = (char*)d_ws;
  float* R    = (float*)(ws + 0);        // 255*256*4 (pad 256K)
  float* a    = (float*)(ws + 262144);   // 512*256*4
  float* bv   = (float*)(ws + 786432);   // 512*256*4
  uint4* WmT2 = (uint4*)(ws + 1310720);  // 32*256*16 = 131072
  uint4* WoPk = (uint4*)(ws + 1441792);  // 512*16

  k_prep<<<133, 512, 0, stream>>>(hs, Wh_w, Wh_b, Wo_w, R, a, bv, WmT2, WoPk);
  k_main<<<2048, 512, 0, stream>>>(hs, mask, R, a, bv, WmT2, WoPk, Wo_b,
                                   (float*)d_out);
}